// Round 1
// baseline (1511.006 us; speedup 1.0000x reference)
//
#include <hip/hip_runtime.h>
#include <stdint.h>

#define M_DIM 8192
#define K_DIM 4096
#define N_DIM 4096

typedef int   i32x4 __attribute__((ext_vector_type(4)));
typedef float f32x4 __attribute__((ext_vector_type(4)));

// async global -> LDS, 16B per active lane; LDS dest = wave-uniform base + lane*16
__device__ __forceinline__ void gload16(const void* g, void* l) {
    __builtin_amdgcn_global_load_lds(
        (const __attribute__((address_space(1))) void*)g,
        (__attribute__((address_space(3))) void*)l,
        16, 0, 0);
}

// ---------------- kernel 1: x fp32 -> int8 with per-row scale ----------------
// one block (256 thr) per row of 4096; xq int8 [M][K], xs fp32 [M]
__global__ __launch_bounds__(256) void conv_x_i8(const float* __restrict__ x,
                                                 int* __restrict__ xq,
                                                 float* __restrict__ xs) {
    int m = blockIdx.x, tid = threadIdx.x;
    const float* row = x + (size_t)m * K_DIM;
    float4 v[4];
    float mx = 0.f;
    #pragma unroll
    for (int i = 0; i < 4; ++i) {
        v[i] = *(const float4*)(row + i * 1024 + tid * 4);
        mx = fmaxf(mx, fmaxf(fmaxf(fabsf(v[i].x), fabsf(v[i].y)),
                             fmaxf(fabsf(v[i].z), fabsf(v[i].w))));
    }
    #pragma unroll
    for (int o = 32; o > 0; o >>= 1) mx = fmaxf(mx, __shfl_xor(mx, o, 64));
    __shared__ float red[4];
    if ((tid & 63) == 0) red[tid >> 6] = mx;
    __syncthreads();
    mx = fmaxf(fmaxf(red[0], red[1]), fmaxf(red[2], red[3]));
    mx = fmaxf(mx, 1e-20f);
    float inv = 127.f / mx;
    if (tid == 0) xs[m] = mx * (1.f / 127.f);
    #pragma unroll
    for (int i = 0; i < 4; ++i) {
        int q0 = (int)__builtin_rintf(v[i].x * inv);
        int q1 = (int)__builtin_rintf(v[i].y * inv);
        int q2 = (int)__builtin_rintf(v[i].z * inv);
        int q3 = (int)__builtin_rintf(v[i].w * inv);
        uint32_t p = (uint32_t)(q0 & 255) | ((uint32_t)(q1 & 255) << 8) |
                     ((uint32_t)(q2 & 255) << 16) | ((uint32_t)q3 << 24);
        xq[(size_t)m * (K_DIM / 4) + i * 256 + tid] = (int)p;
    }
}

// ---------------- kernel 2: dequant -> Wt int8 [N, K], value (w - z) ----------------
#define DLROW 272   // 256 + 16 bytes pad
__global__ __launch_bounds__(256) void dequant_i8(const uint32_t* __restrict__ qw,
                                                  const uint32_t* __restrict__ qz,
                                                  const int* __restrict__ gidx,
                                                  signed char* __restrict__ wt) {
    __shared__ __align__(16) unsigned char lds[64 * DLROW];
    int tid = threadIdx.x;
    int n0  = blockIdx.x * 64;    // 64 n per block
    int k80 = blockIdx.y * 32;    // 32 packed words = 256 k per block

    #pragma unroll
    for (int i = 0; i < 8; ++i) {
        int idx = i * 256 + tid;          // 0..2047
        int k8l = idx >> 6;               // 0..31
        int nl  = idx & 63;               // 0..63
        int k8  = k80 + k8l;
        int nn  = n0 + nl;
        uint32_t w = qw[(size_t)k8 * N_DIM + nn];
        int g = gidx[k8 * 8];
        uint32_t zw = qz[(size_t)g * (N_DIM / 8) + (nn >> 3)];
        int z = (int)((zw >> ((nn & 7) * 4)) & 0xFu);
        uint64_t o = 0;
        #pragma unroll
        for (int j = 0; j < 8; ++j) {
            int wv = (int)((w >> (4 * j)) & 0xFu);
            o |= (uint64_t)(uint8_t)(signed char)(wv - z) << (8 * j);
        }
        *(uint64_t*)&lds[nl * DLROW + k8l * 8] = o;
    }
    __syncthreads();
    #pragma unroll
    for (int i = 0; i < 4; ++i) {
        int idx = i * 256 + tid;          // 1024 chunk tasks
        int row = idx >> 4;               // 0..63
        int c   = idx & 15;               // 16B chunk along k
        i32x4 v = *(const i32x4*)&lds[row * DLROW + c * 16];
        *(i32x4*)&wt[(size_t)(n0 + row) * K_DIM + k80 * 8 + c * 16] = v;
    }
}

// ---------------- kernel 3: int8 GEMM, 256x256 tile, 8-phase pipelined ----------------
// C[M,N] = xs[m] * sum_g s[g,n] * (xq[m,:] . wt[n,:])_int over k-group g (128 k)
// 512 thr = 8 waves (2 m x 4 n), per-wave 128x64 output via 16x16x64 i8 MFMA.
// BK = 128 = one scale group; per phase one C-quadrant (64x32) over full K=128,
// so the int accumulator is group-complete per phase and rescaled there.
// LDS: A,B double-buffered 4x32KB (linear rows of 128B, 16B chunks XOR-swizzled
// by row&7 via pre-swizzled global source) + 2x1KB scale stash.
// Schedule: 8 phases / 2 K-tiles per iteration; each phase: 12 ds_read_b128 +
// 2-3 global_load_lds -> barrier -> lgkmcnt(0) -> setprio(1) 16 MFMA + rescale
// -> counted vmcnt (never 0 in steady state) -> barrier. Staged half-sets:
//   A set0 = rows {0-63,128-191} (dead after ph2 of its reader tile)
//   A set1 = rows {64-127,192-255} (dead after ph4)
//   B set0 = rows {0-31,64-95,128-159,192-223} (dead after ph3)
//   B set1 = complement (dead after ph4)
// Per-iteration staging: P1:Ss+A1(t1) P2:B1(t1) P3:A0(t2) P4:B0(t2)
//                        P5:Ss+A1(t2) P6:B1(t2) P7:A0(t3) P8:B0(t3)
// Waits: endP1 vmcnt(7), endP4 vmcnt(8), endP5 vmcnt(7), endP8 vmcnt(8);
// every staged half has >=3 phases in flight before it is awaited.
#define VMW(n) asm volatile("s_waitcnt vmcnt(" #n ")" ::: "memory")

#define STAGE_A(bufi, t, s, j)                                                   \
    gload16(ga + ((size_t)((s) * 64 + (j) * 128) * K_DIM + (size_t)(t) * 128),   \
            &As[bufi][((((s) * 64 + (j) * 128 + sr)) << 7) + sc * 16])

#define STAGE_B(bufi, t, s, j)                                                   \
    gload16(gb + ((size_t)((s) * 32 + (j) * 128) * K_DIM + (size_t)(t) * 128),   \
            &Bs[bufi][((((s) * 32 + (j) * 128 + brl)) << 7) + sc * 16])

// all 8 waves stage the same 1KB of scales (identical-value writes are benign);
// keeps per-wave vmcnt counts uniform and deterministic.
#define STAGE_S(bufi, t)                                                         \
    gload16(S + (size_t)(t) * N_DIM + bn + lane * 4, &Sl[bufi][lane * 4])

#define PHASE(bufi, mq, nq, STG, TAIL) do {                                      \
    i32x4 af_[4][2], bf_[2][2];                                                  \
    float sv0_ = Sl[bufi][wave_n * 64 + (nq) * 32 + l15];                        \
    float sv1_ = Sl[bufi][wave_n * 64 + (nq) * 32 + 16 + l15];                   \
    _Pragma("unroll")                                                            \
    for (int m4_ = 0; m4_ < 4; ++m4_) {                                          \
        const signed char* p_ =                                                  \
            &As[bufi][(wave_m * 128 + ((mq) * 4 + m4_) * 16 + l15) << 7];        \
        af_[m4_][0] = *(const i32x4*)(p_ + c0);                                  \
        af_[m4_][1] = *(const i32x4*)(p_ + c1);                                  \
    }                                                                            \
    _Pragma("unroll")                                                            \
    for (int n2_ = 0; n2_ < 2; ++n2_) {                                          \
        const signed char* p_ =                                                  \
            &Bs[bufi][(wave_n * 64 + ((nq) * 2 + n2_) * 16 + l15) << 7];         \
        bf_[n2_][0] = *(const i32x4*)(p_ + c0);                                  \
        bf_[n2_][1] = *(const i32x4*)(p_ + c1);                                  \
    }                                                                            \
    STG;                                                                         \
    __builtin_amdgcn_s_barrier();                                                \
    asm volatile("s_waitcnt lgkmcnt(0)" ::: "memory");                           \
    __builtin_amdgcn_s_setprio(1);                                               \
    _Pragma("unroll")                                                            \
    for (int m4_ = 0; m4_ < 4; ++m4_) {                                          \
        _Pragma("unroll")                                                        \
        for (int n2_ = 0; n2_ < 2; ++n2_) {                                      \
            i32x4 t0_ = __builtin_amdgcn_mfma_i32_16x16x64_i8(                   \
                af_[m4_][0], bf_[n2_][0], (i32x4){0, 0, 0, 0}, 0, 0, 0);         \
            i32x4 t1_ = __builtin_amdgcn_mfma_i32_16x16x64_i8(                   \
                af_[m4_][1], bf_[n2_][1], t0_, 0, 0, 0);                         \
            float ss_ = (n2_ ? sv1_ : sv0_);                                     \
            _Pragma("unroll")                                                    \
            for (int r_ = 0; r_ < 4; ++r_)                                       \
                facc[(mq) * 4 + m4_][(nq) * 2 + n2_][r_] += (float)t1_[r_] * ss_;\
        }                                                                        \
    }                                                                            \
    __builtin_amdgcn_s_setprio(0);                                               \
    TAIL;                                                                        \
    __builtin_amdgcn_s_barrier();                                                \
    __builtin_amdgcn_sched_barrier(0);                                           \
} while (0)

__global__ __launch_bounds__(512, 2) void gemm_i8(const signed char* __restrict__ A,
                                                  const signed char* __restrict__ B,
                                                  const float* __restrict__ S,
                                                  const float* __restrict__ XS,
                                                  float* __restrict__ C) {
    __shared__ __align__(16) signed char As[2][256 * 128];
    __shared__ __align__(16) signed char Bs[2][256 * 128];
    __shared__ __align__(16) float Sl[2][256];

    const int tid  = threadIdx.x;
    const int lane = tid & 63;
    const int wid  = tid >> 6;          // 0..7
    const int l15  = lane & 15;
    const int quad = lane >> 4;         // 0..3
    const int wave_m = wid >> 2;        // 0..1
    const int wave_n = wid & 3;         // 0..3
    const int h  = l15 & 7;
    const int c0 = (quad ^ h) * 16;
    const int c1 = ((4 + quad) ^ h) * 16;

    // XCD-aware swizzle: 512 blocks, 64 contiguous output tiles per XCD
    int bid = blockIdx.x;
    int swz = (bid & 7) * 64 + (bid >> 3);
    int bm = (swz >> 4) * 256;          // 32 m-tiles
    int bn = (swz & 15) * 256;          // 16 n-tiles

    // staging constants: thread t covers row sr, 16B chunk sc, global chunk
    // pre-swizzled so LDS stays linear while reads use chunk^(row&7)
    const int sr  = tid >> 3;           // 0..63
    const int sc  = tid & 7;
    const int gch = sc ^ (sr & 7);
    const int brl = (sr & 31) + ((sr >> 5) << 6);   // B-row local base (set0 j0)
    const signed char* ga = A + (size_t)(bm + sr) * K_DIM + gch * 16;
    const signed char* gb = B + (size_t)(bn + brl) * K_DIM + gch * 16;

    f32x4 facc[8][4];
    #pragma unroll
    for (int i = 0; i < 8; ++i)
        #pragma unroll
        for (int j = 0; j < 4; ++j)
            facc[i][j] = (f32x4){0.f, 0.f, 0.f, 0.f};

    // prologue: scales(t0), tile0 full, tile1 A0+B0; wait all but tile1's 4
    STAGE_S(0, 0);
    STAGE_A(0, 0, 0, 0); STAGE_A(0, 0, 0, 1);
    STAGE_B(0, 0, 0, 0); STAGE_B(0, 0, 0, 1);
    STAGE_A(0, 0, 1, 0); STAGE_A(0, 0, 1, 1);
    STAGE_B(0, 0, 1, 0); STAGE_B(0, 0, 1, 1);
    STAGE_A(1, 1, 0, 0); STAGE_A(1, 1, 0, 1);
    STAGE_B(1, 1, 0, 0); STAGE_B(1, 1, 0, 1);
    VMW(4);
    __builtin_amdgcn_s_barrier();
    __builtin_amdgcn_sched_barrier(0);

    #pragma clang loop unroll(disable)
    for (int it = 0; it < 16; ++it) {
        const int t1k = 2 * it + 1;     // odd tile of this iteration
        const bool nl = (it < 15);

        // P1: quadrant (m0,n0) of buf0
        PHASE(0, 0, 0,
              { STAGE_S(1, t1k); STAGE_A(1, t1k, 1, 0); STAGE_A(1, t1k, 1, 1); },
              { VMW(7); });
        // P2: (m0,n1)
        PHASE(0, 0, 1,
              { STAGE_B(1, t1k, 1, 0); STAGE_B(1, t1k, 1, 1); },
              {});
        // P3: (m1,n0)
        PHASE(0, 1, 0,
              { if (nl) { STAGE_A(0, t1k + 1, 0, 0); STAGE_A(0, t1k + 1, 0, 1); } },
              {});
        // P4: (m1,n1)
        PHASE(0, 1, 1,
              { if (nl) { STAGE_B(0, t1k + 1, 0, 0); STAGE_B(0, t1k + 1, 0, 1); } },
              { if (nl) { VMW(8); } else { VMW(0); } });
        // P5: (m0,n0) of buf1
        PHASE(1, 0, 0,
              { if (nl) { STAGE_S(0, t1k + 1);
                          STAGE_A(0, t1k + 1, 1, 0); STAGE_A(0, t1k + 1, 1, 1); } },
              { if (nl) { VMW(7); } });
        // P6: (m0,n1)
        PHASE(1, 0, 1,
              { if (nl) { STAGE_B(0, t1k + 1, 1, 0); STAGE_B(0, t1k + 1, 1, 1); } },
              {});
        // P7: (m1,n0)
        PHASE(1, 1, 0,
              { if (nl) { STAGE_A(1, t1k + 2, 0, 0); STAGE_A(1, t1k + 2, 0, 1); } },
              {});
        // P8: (m1,n1)
        PHASE(1, 1, 1,
              { if (nl) { STAGE_B(1, t1k + 2, 0, 0); STAGE_B(1, t1k + 2, 0, 1); } },
              { if (nl) { VMW(8); } });
    }

    // epilogue: C/D layout col = lane&15 (n), row = quad*4 + r (m)
    #pragma unroll
    for (int mf = 0; mf < 8; ++mf) {
        int row0 = bm + wave_m * 128 + mf * 16 + quad * 4;
        float4 xsv = *(const float4*)(XS + row0);
        #pragma unroll
        for (int nf = 0; nf < 4; ++nf) {
            int col = bn + wave_n * 64 + nf * 16 + l15;
            C[(size_t)(row0 + 0) * N_DIM + col] = facc[mf][nf][0] * xsv.x;
            C[(size_t)(row0 + 1) * N_DIM + col] = facc[mf][nf][1] * xsv.y;
            C[(size_t)(row0 + 2) * N_DIM + col] = facc[mf][nf][2] * xsv.z;
            C[(size_t)(row0 + 3) * N_DIM + col] = facc[mf][nf][3] * xsv.w;
        }
    }
}

extern "C" void kernel_launch(void* const* d_in, const int* in_sizes, int n_in,
                              void* d_out, int out_size, void* d_ws, size_t ws_size,
                              hipStream_t stream) {
    const float*    x    = (const float*)d_in[0];
    const uint32_t* qw   = (const uint32_t*)d_in[1];
    const uint32_t* qz   = (const uint32_t*)d_in[2];
    const float*    sc   = (const float*)d_in[3];
    const int*      gidx = (const int*)d_in[4];
    float* out = (float*)d_out;

    signed char* xq = (signed char*)d_ws;                          // [M][K] int8, 32 MB
    signed char* wt = xq + (size_t)M_DIM * K_DIM;                  // [N][K] int8, 16 MB
    float*       xs = (float*)(wt + (size_t)N_DIM * K_DIM);        // [M] fp32

    conv_x_i8<<<dim3(M_DIM), 256, 0, stream>>>(x, (int*)xq, xs);
    dequant_i8<<<dim3(N_DIM / 64, K_DIM / 256), 256, 0, stream>>>(qw, qz, gidx, wt);
    gemm_i8<<<dim3(512), dim3(512), 0, stream>>>(xq, wt, sc, xs, out);
}

// Round 2
// 475.298 us; speedup vs baseline: 3.1791x; 3.1791x over previous
//
#include <hip/hip_runtime.h>
#include <stdint.h>

#define M_DIM 8192
#define K_DIM 4096
#define N_DIM 4096

typedef int   i32x4 __attribute__((ext_vector_type(4)));
typedef float f32x4 __attribute__((ext_vector_type(4)));

// async global -> LDS, 16B per active lane; LDS dest = wave-uniform base + lane*16
__device__ __forceinline__ void gload16(const void* g, void* l) {
    __builtin_amdgcn_global_load_lds(
        (const __attribute__((address_space(1))) void*)g,
        (__attribute__((address_space(3))) void*)l,
        16, 0, 0);
}

// ---------------- kernel 1: x fp32 -> int8 with per-row scale ----------------
__global__ __launch_bounds__(256) void conv_x_i8(const float* __restrict__ x,
                                                 int* __restrict__ xq,
                                                 float* __restrict__ xs) {
    int m = blockIdx.x, tid = threadIdx.x;
    const float* row = x + (size_t)m * K_DIM;
    float4 v[4];
    float mx = 0.f;
    #pragma unroll
    for (int i = 0; i < 4; ++i) {
        v[i] = *(const float4*)(row + i * 1024 + tid * 4);
        mx = fmaxf(mx, fmaxf(fmaxf(fabsf(v[i].x), fabsf(v[i].y)),
                             fmaxf(fabsf(v[i].z), fabsf(v[i].w))));
    }
    #pragma unroll
    for (int o = 32; o > 0; o >>= 1) mx = fmaxf(mx, __shfl_xor(mx, o, 64));
    __shared__ float red[4];
    if ((tid & 63) == 0) red[tid >> 6] = mx;
    __syncthreads();
    mx = fmaxf(fmaxf(red[0], red[1]), fmaxf(red[2], red[3]));
    mx = fmaxf(mx, 1e-20f);
    float inv = 127.f / mx;
    if (tid == 0) xs[m] = mx * (1.f / 127.f);
    #pragma unroll
    for (int i = 0; i < 4; ++i) {
        int q0 = (int)__builtin_rintf(v[i].x * inv);
        int q1 = (int)__builtin_rintf(v[i].y * inv);
        int q2 = (int)__builtin_rintf(v[i].z * inv);
        int q3 = (int)__builtin_rintf(v[i].w * inv);
        uint32_t p = (uint32_t)(q0 & 255) | ((uint32_t)(q1 & 255) << 8) |
                     ((uint32_t)(q2 & 255) << 16) | ((uint32_t)q3 << 24);
        xq[(size_t)m * (K_DIM / 4) + i * 256 + tid] = (int)p;
    }
}

// ---------------- kernel 2: dequant -> Wt int8 [N, K], value (w - z) ----------------
#define DLROW 272   // 256 + 16 bytes pad
__global__ __launch_bounds__(256) void dequant_i8(const uint32_t* __restrict__ qw,
                                                  const uint32_t* __restrict__ qz,
                                                  const int* __restrict__ gidx,
                                                  signed char* __restrict__ wt) {
    __shared__ __align__(16) unsigned char lds[64 * DLROW];
    int tid = threadIdx.x;
    int n0  = blockIdx.x * 64;
    int k80 = blockIdx.y * 32;

    #pragma unroll
    for (int i = 0; i < 8; ++i) {
        int idx = i * 256 + tid;
        int k8l = idx >> 6;
        int nl  = idx & 63;
        int k8  = k80 + k8l;
        int nn  = n0 + nl;
        uint32_t w = qw[(size_t)k8 * N_DIM + nn];
        int g = gidx[k8 * 8];
        uint32_t zw = qz[(size_t)g * (N_DIM / 8) + (nn >> 3)];
        int z = (int)((zw >> ((nn & 7) * 4)) & 0xFu);
        uint64_t o = 0;
        #pragma unroll
        for (int j = 0; j < 8; ++j) {
            int wv = (int)((w >> (4 * j)) & 0xFu);
            o |= (uint64_t)(uint8_t)(signed char)(wv - z) << (8 * j);
        }
        *(uint64_t*)&lds[nl * DLROW + k8l * 8] = o;
    }
    __syncthreads();
    #pragma unroll
    for (int i = 0; i < 4; ++i) {
        int idx = i * 256 + tid;
        int row = idx >> 4;
        int c   = idx & 15;
        i32x4 v = *(const i32x4*)&lds[row * DLROW + c * 16];
        *(i32x4*)&wt[(size_t)(n0 + row) * K_DIM + k80 * 8 + c * 16] = v;
    }
}

// ---------------- kernel 3: int8 GEMM, 256x128 tile, 8-phase pipelined ----------------
// 512 thr = 8 waves (4 m x 2 n), per-wave 64x64 output -> facc[4][4] = 64 regs/lane
// (register-safe; the 256x256 variant spilled: 128 acc regs + 128-VGPR alloc).
// BK = 128 = one scale group; phase = quadrant (mq,nq) of the wave's 4x4 tile grid,
// full K=128 chained, so int acc is group-complete per phase, rescaled there.
// Staged half-sets (rows r of the LDS tile):
//   A set0 = (r&63)<32  read P1,P2 (mq=0) ; A set1 read P3,P4
//   B set0 = (r&63)<32  read P1,P3 (nq=0) ; B set1 read P2,P4
// Per-iteration staging (tiles t=2i buf0 @P1-4, t+1 buf1 @P5-8):
//   P1: S(t+2,t+3)+A1(t+1)x2  P2: B1(t+1)  P3: A0(t+2)x2  P4: B0(t+2)
//   P5: A1(t+2)x2             P6: B1(t+2)  P7: A0(t+3)x2  P8: B0(t+3)
// Counted waits (steady): endP1 vmcnt(6), endP4 vmcnt(7), endP5 vmcnt(5),
// endP8 vmcnt(6); every staged item >=3 phases in flight; drain only in tail.
#define VMW(n) asm volatile("s_waitcnt vmcnt(" #n ")" ::: "memory")

#define STAGE_A(bufi, t, s, j)                                                   \
    gload16(ga + ((size_t)((s) * 32 + (j) * 128) * K_DIM + (size_t)(t) * 128),   \
            &As[bufi][((((s) * 32 + (j) * 128 + brl)) << 7) + sc * 16])

#define STAGE_B(bufi, t, s)                                                      \
    gload16(gb + ((size_t)((s) * 32) * K_DIM + (size_t)(t) * 128),               \
            &Bs[bufi][((((s) * 32 + brl)) << 7) + sc * 16])

// scales for tile-pair (t, t+1): 2 x 512B = 1KB, all 8 waves stage the same data
// (identical-value writes benign; keeps per-wave vmcnt uniform). lane<32 -> row t,
// lane>=32 -> row t+1 (global source is per-lane; LDS dest linear).
#define STAGE_S(p, t)                                                            \
    gload16(S + (size_t)((t) + (lane >> 5)) * N_DIM + bn + (lane & 31) * 4,      \
            &Sl[p][lane * 4])

#define PHASE(bufi, p, mq, nq, STG, TAIL) do {                                   \
    i32x4 af_[2][2], bf_[2][2];                                                  \
    float sv0_ = Sl[p][(bufi) * 128 + wave_n * 64 + (nq) * 32 + l15];            \
    float sv1_ = Sl[p][(bufi) * 128 + wave_n * 64 + (nq) * 32 + 16 + l15];       \
    _Pragma("unroll")                                                            \
    for (int m2_ = 0; m2_ < 2; ++m2_) {                                          \
        const signed char* p_ =                                                  \
            &As[bufi][(wave_m * 64 + ((mq) * 2 + m2_) * 16 + l15) << 7];         \
        af_[m2_][0] = *(const i32x4*)(p_ + c0);                                  \
        af_[m2_][1] = *(const i32x4*)(p_ + c1);                                  \
    }                                                                            \
    _Pragma("unroll")                                                            \
    for (int n2_ = 0; n2_ < 2; ++n2_) {                                          \
        const signed char* p_ =                                                  \
            &Bs[bufi][(wave_n * 64 + ((nq) * 2 + n2_) * 16 + l15) << 7];         \
        bf_[n2_][0] = *(const i32x4*)(p_ + c0);                                  \
        bf_[n2_][1] = *(const i32x4*)(p_ + c1);                                  \
    }                                                                            \
    STG;                                                                         \
    __builtin_amdgcn_s_barrier();                                                \
    asm volatile("s_waitcnt lgkmcnt(0)" ::: "memory");                           \
    __builtin_amdgcn_s_setprio(1);                                               \
    _Pragma("unroll")                                                            \
    for (int m2_ = 0; m2_ < 2; ++m2_) {                                          \
        _Pragma("unroll")                                                        \
        for (int n2_ = 0; n2_ < 2; ++n2_) {                                      \
            i32x4 t0_ = __builtin_amdgcn_mfma_i32_16x16x64_i8(                   \
                af_[m2_][0], bf_[n2_][0], (i32x4){0, 0, 0, 0}, 0, 0, 0);         \
            i32x4 t1_ = __builtin_amdgcn_mfma_i32_16x16x64_i8(                   \
                af_[m2_][1], bf_[n2_][1], t0_, 0, 0, 0);                         \
            float ss_ = (n2_ ? sv1_ : sv0_);                                     \
            _Pragma("unroll")                                                    \
            for (int r_ = 0; r_ < 4; ++r_)                                       \
                facc[(mq) * 2 + m2_][(nq) * 2 + n2_][r_] += (float)t1_[r_] * ss_;\
        }                                                                        \
    }                                                                            \
    __builtin_amdgcn_s_setprio(0);                                               \
    TAIL;                                                                        \
    __builtin_amdgcn_s_barrier();                                                \
    __builtin_amdgcn_sched_barrier(0);                                           \
} while (0)

__global__ __launch_bounds__(512, 2) void gemm_i8(const signed char* __restrict__ A,
                                                  const signed char* __restrict__ B,
                                                  const float* __restrict__ S,
                                                  const float* __restrict__ XS,
                                                  float* __restrict__ C) {
    __shared__ __align__(16) signed char As[2][256 * 128];   // 64 KB
    __shared__ __align__(16) signed char Bs[2][128 * 128];   // 32 KB
    __shared__ __align__(16) float Sl[2][256];               //  2 KB

    const int tid  = threadIdx.x;
    const int lane = tid & 63;
    const int wid  = tid >> 6;          // 0..7
    const int l15  = lane & 15;
    const int quad = lane >> 4;         // 0..3
    const int wave_m = wid >> 1;        // 0..3
    const int wave_n = wid & 1;         // 0..1
    const int h  = l15 & 7;
    const int c0 = (quad ^ h) * 16;
    const int c1 = ((4 + quad) ^ h) * 16;

    // XCD-aware swizzle: 1024 blocks, 128 contiguous tiles per XCD
    // (4 m-rows x 32 n per XCD -> A panel 4 MB fits the XCD L2)
    int bid = blockIdx.x;
    int swz = (bid & 7) * 128 + (bid >> 3);
    int bm = (swz >> 5) * 256;          // 32 m-tiles
    int bn = (swz & 31) * 128;          // 32 n-tiles

    // staging: thread t covers row brl(+set offsets), 16B chunk sc; global chunk
    // pre-swizzled so LDS stays linear while fragment reads use chunk^(row&7)
    const int sr  = tid >> 3;                        // 0..63
    const int sc  = tid & 7;
    const int gch = sc ^ (sr & 7);
    const int brl = (sr & 31) + ((sr >> 5) << 6);    // rows [0,32) u [64,96)
    const signed char* ga = A + (size_t)(bm + brl) * K_DIM + gch * 16;
    const signed char* gb = B + (size_t)(bn + brl) * K_DIM + gch * 16;

    f32x4 facc[4][4];
    #pragma unroll
    for (int i = 0; i < 4; ++i)
        #pragma unroll
        for (int j = 0; j < 4; ++j)
            facc[i][j] = (f32x4){0.f, 0.f, 0.f, 0.f};

    // prologue: S(t0,t1); t0 full; t1 early sets; leave exactly the steady-state
    // 6 in flight: [A1(t0)x2, B1(t0), A0(t1)x2, B0(t1)]
    STAGE_S(0, 0);
    STAGE_A(0, 0, 0, 0); STAGE_A(0, 0, 0, 1);
    STAGE_B(0, 0, 0);
    STAGE_A(0, 0, 1, 0); STAGE_A(0, 0, 1, 1);
    STAGE_B(0, 0, 1);
    STAGE_A(1, 1, 0, 0); STAGE_A(1, 1, 0, 1);
    STAGE_B(1, 1, 0);
    VMW(6);
    __builtin_amdgcn_s_barrier();
    __builtin_amdgcn_sched_barrier(0);

    #pragma clang loop unroll(disable)
    for (int it = 0; it < 16; ++it) {
        const int t0k = 2 * it;         // even tile (buf0)
        const int t1k = 2 * it + 1;     // odd tile (buf1)
        const bool nl = (it < 15);
        const int p = it & 1;

        // P1: (m0,n0) buf0
        PHASE(0, p, 0, 0,
              { if (nl) { STAGE_S(p ^ 1, t0k + 2); }
                STAGE_A(1, t1k, 1, 0); STAGE_A(1, t1k, 1, 1); },
              { if (nl) { VMW(6); } else { VMW(5); } });
        // P2: (m0,n1)
        PHASE(0, p, 0, 1,
              { STAGE_B(1, t1k, 1); },
              {});
        // P3: (m1,n0)
        PHASE(0, p, 1, 0,
              { if (nl) { STAGE_A(0, t0k + 2, 0, 0); STAGE_A(0, t0k + 2, 0, 1); } },
              {});
        // P4: (m1,n1)
        PHASE(0, p, 1, 1,
              { if (nl) { STAGE_B(0, t0k + 2, 0); } },
              { if (nl) { VMW(7); } else { VMW(3); } });
        // P5: (m0,n0) buf1
        PHASE(1, p, 0, 0,
              { if (nl) { STAGE_A(0, t0k + 2, 1, 0); STAGE_A(0, t0k + 2, 1, 1); } },
              { if (nl) { VMW(5); } else { VMW(0); } });
        // P6: (m0,n1)
        PHASE(1, p, 0, 1,
              { if (nl) { STAGE_B(0, t0k + 2, 1); } },
              {});
        // P7: (m1,n0)
        PHASE(1, p, 1, 0,
              { if (nl) { STAGE_A(1, t1k + 2, 0, 0); STAGE_A(1, t1k + 2, 0, 1); } },
              {});
        // P8: (m1,n1)
        PHASE(1, p, 1, 1,
              { if (nl) { STAGE_B(1, t1k + 2, 0); } },
              { if (nl) { VMW(6); } });
    }

    // epilogue: C/D layout col = lane&15 (n), row = quad*4 + r (m)
    #pragma unroll
    for (int mt = 0; mt < 4; ++mt) {
        int row0 = bm + wave_m * 64 + mt * 16 + quad * 4;
        float4 xsv = *(const float4*)(XS + row0);
        #pragma unroll
        for (int nt = 0; nt < 4; ++nt) {
            int col = bn + wave_n * 64 + nt * 16 + l15;
            C[(size_t)(row0 + 0) * N_DIM + col] = facc[mt][nt][0] * xsv.x;
            C[(size_t)(row0 + 1) * N_DIM + col] = facc[mt][nt][1] * xsv.y;
            C[(size_t)(row0 + 2) * N_DIM + col] = facc[mt][nt][2] * xsv.z;
            C[(size_t)(row0 + 3) * N_DIM + col] = facc[mt][nt][3] * xsv.w;
        }
    }
}

extern "C" void kernel_launch(void* const* d_in, const int* in_sizes, int n_in,
                              void* d_out, int out_size, void* d_ws, size_t ws_size,
                              hipStream_t stream) {
    const float*    x    = (const float*)d_in[0];
    const uint32_t* qw   = (const uint32_t*)d_in[1];
    const uint32_t* qz   = (const uint32_t*)d_in[2];
    const float*    sc   = (const float*)d_in[3];
    const int*      gidx = (const int*)d_in[4];
    float* out = (float*)d_out;

    signed char* xq = (signed char*)d_ws;                          // [M][K] int8, 32 MB
    signed char* wt = xq + (size_t)M_DIM * K_DIM;                  // [N][K] int8, 16 MB
    float*       xs = (float*)(wt + (size_t)N_DIM * K_DIM);        // [M] fp32

    conv_x_i8<<<dim3(M_DIM), 256, 0, stream>>>(x, (int*)xq, xs);
    dequant_i8<<<dim3(N_DIM / 64, K_DIM / 256), 256, 0, stream>>>(qw, qz, gidx, wt);
    gemm_i8<<<dim3(1024), dim3(512), 0, stream>>>(xq, wt, sc, xs, out);
}